// Round 1
// baseline (867.176 us; speedup 1.0000x reference)
//
#include <hip/hip_runtime.h>

typedef unsigned short u16;
typedef __attribute__((ext_vector_type(8))) short s16x8;
typedef __attribute__((ext_vector_type(4))) float f32x4;

#define DEVI static __device__ __forceinline__

constexpr int BATCH = 2;
constexpr int SEQ   = 2048;
constexpr int EMB   = 4096;
constexpr int NQ    = 32;
constexpr int NKV   = 8;
constexpr int HD    = 128;
constexpr int KVD   = 1024;
constexpr int MR    = BATCH * SEQ;   // 4096 rows for all projections

// ---------- helpers ----------

DEVI u16 f2bf(float f) {             // RNE float -> bf16 (finite inputs)
  union { float f; unsigned u; } x; x.f = f;
  unsigned r = x.u + 0x7FFFu + ((x.u >> 16) & 1u);
  return (u16)(r >> 16);
}

DEVI void mfma_acc(f32x4& c, s16x8 a, s16x8 b) {
  // D == C in-place accumulate; inline asm avoids builtin operand-type ambiguity
  asm volatile("v_mfma_f32_16x16x32_bf16 %0, %1, %2, %0" : "+v"(c) : "v"(a), "v"(b));
}

DEVI void gload16(const void* g, void* l) {
  __builtin_amdgcn_global_load_lds(
      (const __attribute__((address_space(1))) void*)g,
      (__attribute__((address_space(3))) void*)l, 16, 0, 0);
}

DEVI float fexp2(float x) {
#if __has_builtin(__builtin_amdgcn_exp2f)
  return __builtin_amdgcn_exp2f(x);
#else
  return exp2f(x);
#endif
}

DEVI void store_out(u16* C, size_t idx, float v)   { C[idx] = f2bf(v); }
DEVI void store_out(float* C, size_t idx, float v) { C[idx] = v; }

// ---------- elementwise f32 -> bf16 ----------

__global__ __launch_bounds__(256) void cvt_f32_bf16(const float* __restrict__ in,
                                                    u16* __restrict__ out, int n8) {
  int i = blockIdx.x * 256 + threadIdx.x;
  if (i >= n8) return;
  const float4* p4 = (const float4*)in;
  float4 a = p4[2 * (size_t)i], b = p4[2 * (size_t)i + 1];
  u16 t[8];
  t[0] = f2bf(a.x); t[1] = f2bf(a.y); t[2] = f2bf(a.z); t[3] = f2bf(a.w);
  t[4] = f2bf(b.x); t[5] = f2bf(b.y); t[6] = f2bf(b.z); t[7] = f2bf(b.w);
  *(s16x8*)(out + 8 * (size_t)i) = *(const s16x8*)t;
}

// ---------- W[K][N] f32 -> Wt[N][K] bf16 (transpose + convert) ----------

__global__ __launch_bounds__(256) void transp_cvt(const float* __restrict__ W,
                                                  u16* __restrict__ Wt,
                                                  int Kd, int Nd) {
  __shared__ u16 tile[32][33];
  int tx = threadIdx.x, ty = threadIdx.y;
  int n0 = blockIdx.x * 32, k0 = blockIdx.y * 32;
#pragma unroll
  for (int j = 0; j < 4; ++j)
    tile[ty + 8 * j][tx] = f2bf(W[(size_t)(k0 + ty + 8 * j) * Nd + n0 + tx]);
  __syncthreads();
#pragma unroll
  for (int j = 0; j < 4; ++j)
    Wt[(size_t)(n0 + ty + 8 * j) * Kd + k0 + tx] = tile[tx][ty + 8 * j];
}

// ---------- Vp[B,S,KVD] bf16 -> Vt[B*NKV][HD][SEQ] bf16 ----------

__global__ __launch_bounds__(256) void transp_v(const u16* __restrict__ Vp,
                                                u16* __restrict__ Vt) {
  __shared__ u16 tile[32][33];
  int tx = threadIdx.x, ty = threadIdx.y;
  int bh = blockIdx.z, b = bh >> 3, h = bh & 7;
  int s0 = blockIdx.x * 32, d0 = blockIdx.y * 32;
  const u16* src = Vp + (size_t)b * SEQ * KVD + h * HD;
#pragma unroll
  for (int j = 0; j < 4; ++j)
    tile[ty + 8 * j][tx] = src[(size_t)(s0 + ty + 8 * j) * KVD + d0 + tx];
  __syncthreads();
  u16* dst = Vt + (size_t)bh * HD * SEQ;
#pragma unroll
  for (int j = 0; j < 4; ++j)
    dst[(size_t)(d0 + ty + 8 * j) * SEQ + s0 + tx] = tile[tx][ty + 8 * j];
}

// ---------- GEMM: C[M][N] = A[M][K] * Bt[N][K]^T + bias, bf16 MFMA ----------
// 128x128 tile, BK=32, 4 waves (2x2 of 64x64), global_load_lds(16B) staging
// with XOR chunk swizzle: LDS[row][c] = G[row][c ^ f(row)], f = (r^(r>>2))&3.

template <typename OT>
__global__ __launch_bounds__(256) void gemm_bt(const u16* __restrict__ A,
                                               const u16* __restrict__ Bt,
                                               const float* __restrict__ bias,
                                               OT* __restrict__ C,
                                               int M, int N, int K) {
  __shared__ __align__(16) u16 As[128 * 32];
  __shared__ __align__(16) u16 Bs[128 * 32];
  const int tid = threadIdx.x;
  const int lane = tid & 63, w = tid >> 6;
  const int wr = w >> 1, wc = w & 1;
  const int l15 = lane & 15, g = lane >> 4;
  const int m0 = blockIdx.y * 128, n0 = blockIdx.x * 128;
  const int srow = lane >> 2, schunk = lane & 3;          // staging: 16 rows x 4 chunks
  const int fsw = (srow ^ (srow >> 2)) & 3;               // swizzle (depends on row&15)
  const int fr  = (l15  ^ (l15  >> 2)) & 3;

  f32x4 acc[4][4] = {};

  const u16* Ag = A  + (size_t)(m0 + w * 32 + srow) * K + ((schunk ^ fsw) << 3);
  const u16* Bg = Bt + (size_t)(n0 + w * 32 + srow) * K + ((schunk ^ fsw) << 3);
  u16* Al = As + (w * 32) * 32;   // wave-uniform LDS bases
  u16* Bl = Bs + (w * 32) * 32;

  for (int k0 = 0; k0 < K; k0 += 32) {
    __syncthreads();
    gload16(Ag + k0,                    Al);
    gload16(Ag + (size_t)16 * K + k0,   Al + 16 * 32);
    gload16(Bg + k0,                    Bl);
    gload16(Bg + (size_t)16 * K + k0,   Bl + 16 * 32);
    __syncthreads();

    s16x8 af[4], bfr[4];
#pragma unroll
    for (int rt = 0; rt < 4; ++rt)
      af[rt] = *(const s16x8*)(As + (wr * 64 + rt * 16 + l15) * 32 + ((g ^ fr) << 3));
#pragma unroll
    for (int ct = 0; ct < 4; ++ct)
      bfr[ct] = *(const s16x8*)(Bs + (wc * 64 + ct * 16 + l15) * 32 + ((g ^ fr) << 3));
#pragma unroll
    for (int rt = 0; rt < 4; ++rt)
#pragma unroll
      for (int ct = 0; ct < 4; ++ct)
        mfma_acc(acc[rt][ct], af[rt], bfr[ct]);
  }

#pragma unroll
  for (int ct = 0; ct < 4; ++ct) {
    const int col = n0 + wc * 64 + ct * 16 + l15;
    const float bv = bias[col];
#pragma unroll
    for (int rt = 0; rt < 4; ++rt) {
      const int row = m0 + wr * 64 + rt * 16 + g * 4;
#pragma unroll
      for (int i = 0; i < 4; ++i)
        store_out(C, (size_t)(row + i) * N + col, acc[rt][ct][i] + bv);
    }
  }
}

// ---------- flash attention (GQA, no mask) ----------
// Grid: (SEQ/128, BATCH*NQ). 4 waves x 32 q-rows. KV chunk = 64.
// Q bf16 [B*S][EMB], Kp bf16 [B*S][KVD], Vt bf16 [B*NKV][HD][SEQ], Y bf16 [B*S][EMB].

__global__ __launch_bounds__(256) void attn(const u16* __restrict__ Q,
                                            const u16* __restrict__ Kp,
                                            const u16* __restrict__ Vt,
                                            u16* __restrict__ Y) {
  __shared__ __align__(16) u16 Kl[64][136];    // [kv][d], +8 pad
  __shared__ __align__(16) u16 Vl[128][72];    // [d][kv], +8 pad
  __shared__ __align__(16) u16 Pl[4][32][72];  // per-wave P [q][kv], +8 pad

  const int tid = threadIdx.x, lane = tid & 63, w = tid >> 6;
  const int l15 = lane & 15, g = lane >> 4;
  const int bz = blockIdx.y, b = bz >> 5, qh = bz & 31, h = qh >> 2;
  const int q0 = blockIdx.x * 128;
  constexpr float C1 = 0.08838834764831845f * 1.4426950408889634f; // scale*log2(e)

  // Q fragments held in registers for the whole kernel
  s16x8 qf[2][4];
  const u16* qptr = Q + (size_t)(b * SEQ + q0 + w * 32) * EMB + qh * HD;
#pragma unroll
  for (int rt = 0; rt < 2; ++rt)
#pragma unroll
    for (int ks = 0; ks < 4; ++ks)
      qf[rt][ks] = *(const s16x8*)(qptr + (size_t)(rt * 16 + l15) * EMB + ks * 32 + g * 8);

  f32x4 o[2][8] = {};
  float m_[2][4], l_[2][4];
#pragma unroll
  for (int rt = 0; rt < 2; ++rt)
#pragma unroll
    for (int i = 0; i < 4; ++i) { m_[rt][i] = -1e30f; l_[rt][i] = 0.f; }

  const u16* kbase = Kp + (size_t)b * SEQ * KVD + h * HD;
  const u16* vbase = Vt + (size_t)(b * NKV + h) * HD * SEQ;

  for (int kv0 = 0; kv0 < SEQ; kv0 += 64) {
    __syncthreads();
    { // stage K chunk [64][128] and V^T chunk [128][64]
      int r = tid >> 4, c = (tid & 15) * 8;
#pragma unroll
      for (int p = 0; p < 4; ++p)
        *(s16x8*)&Kl[r + p * 16][c] =
            *(const s16x8*)(kbase + (size_t)(kv0 + r + p * 16) * KVD + c);
      int r2 = tid >> 3, c2 = (tid & 7) * 8;
#pragma unroll
      for (int p = 0; p < 4; ++p)
        *(s16x8*)&Vl[r2 + p * 32][c2] =
            *(const s16x8*)(vbase + (size_t)(r2 + p * 32) * SEQ + kv0 + c2);
    }
    __syncthreads();

    // S = Q K^T  (2 row-tiles x 4 col-tiles of 16x16)
    f32x4 sa[2][4] = {};
#pragma unroll
    for (int ks = 0; ks < 4; ++ks) {
      s16x8 kf[4];
#pragma unroll
      for (int ct = 0; ct < 4; ++ct)
        kf[ct] = *(const s16x8*)&Kl[ct * 16 + l15][ks * 32 + g * 8];
#pragma unroll
      for (int rt = 0; rt < 2; ++rt)
#pragma unroll
        for (int ct = 0; ct < 4; ++ct)
          mfma_acc(sa[rt][ct], qf[rt][ks], kf[ct]);
    }

    // online softmax (rows rt*16 + g*4 + i; 16-lane shuffle reduce over cols)
#pragma unroll
    for (int rt = 0; rt < 2; ++rt) {
      float mx[4], rs[4];
#pragma unroll
      for (int i = 0; i < 4; ++i) {
        float t = fmaxf(fmaxf(sa[rt][0][i], sa[rt][1][i]),
                        fmaxf(sa[rt][2][i], sa[rt][3][i]));
        mx[i] = t * C1;
      }
#pragma unroll
      for (int off = 1; off < 16; off <<= 1)
#pragma unroll
        for (int i = 0; i < 4; ++i)
          mx[i] = fmaxf(mx[i], __shfl_xor(mx[i], off));
#pragma unroll
      for (int i = 0; i < 4; ++i) {
        float mn = fmaxf(m_[rt][i], mx[i]);
        float al = fexp2(m_[rt][i] - mn);
        m_[rt][i] = mn;
        rs[i] = 0.f;
#pragma unroll
        for (int ct = 0; ct < 4; ++ct) {
          float pv = fexp2(sa[rt][ct][i] * C1 - mn);
          rs[i] += pv;
          Pl[w][rt * 16 + g * 4 + i][ct * 16 + l15] = f2bf(pv);
        }
        l_[rt][i] *= al;
#pragma unroll
        for (int ctd = 0; ctd < 8; ++ctd)
          o[rt][ctd][i] *= al;
      }
#pragma unroll
      for (int off = 1; off < 16; off <<= 1)
#pragma unroll
        for (int i = 0; i < 4; ++i)
          rs[i] += __shfl_xor(rs[i], off);
#pragma unroll
      for (int i = 0; i < 4; ++i) l_[rt][i] += rs[i];
    }
    __syncthreads();  // P stores visible/ordered before fragment reads

    // O += P V
#pragma unroll
    for (int ks2 = 0; ks2 < 2; ++ks2) {
      s16x8 pf[2];
#pragma unroll
      for (int rt = 0; rt < 2; ++rt)
        pf[rt] = *(const s16x8*)&Pl[w][rt * 16 + l15][ks2 * 32 + g * 8];
#pragma unroll
      for (int ctd = 0; ctd < 8; ++ctd) {
        s16x8 vf = *(const s16x8*)&Vl[ctd * 16 + l15][ks2 * 32 + g * 8];
#pragma unroll
        for (int rt = 0; rt < 2; ++rt)
          mfma_acc(o[rt][ctd], pf[rt], vf);
      }
    }
  }

  // normalize + write Y (bf16)
  u16* yptr = Y + (size_t)(b * SEQ + q0 + w * 32) * EMB + qh * HD;
#pragma unroll
  for (int rt = 0; rt < 2; ++rt)
#pragma unroll
    for (int i = 0; i < 4; ++i) {
      float inv = 1.f / l_[rt][i];
#pragma unroll
      for (int ctd = 0; ctd < 8; ++ctd)
        yptr[(size_t)(rt * 16 + g * 4 + i) * EMB + ctd * 16 + l15] =
            f2bf(o[rt][ctd][i] * inv);
    }
}

// ---------- launch ----------

extern "C" void kernel_launch(void* const* d_in, const int* in_sizes, int n_in,
                              void* d_out, int out_size, void* d_ws, size_t ws_size,
                              hipStream_t stream) {
  (void)in_sizes; (void)n_in; (void)out_size;
  const float* q_in = (const float*)d_in[0];
  const float* k_in = (const float*)d_in[1];
  const float* v_in = (const float*)d_in[2];
  const float* Wq = (const float*)d_in[3];
  const float* bq = (const float*)d_in[4];
  const float* Wk = (const float*)d_in[5];
  const float* bk = (const float*)d_in[6];
  const float* Wv = (const float*)d_in[7];
  const float* bv = (const float*)d_in[8];
  const float* Wo = (const float*)d_in[9];
  const float* bo = (const float*)d_in[10];
  float* out = (float*)d_out;

  char* base = (char*)d_ws;
  size_t off = 0;
  auto alloc = [&](size_t bytes) -> void* {
    void* r = base + off;
    off += (bytes + 255) & ~(size_t)255;
    return r;
  };
  u16* qb  = (u16*)alloc((size_t)MR * EMB * 2);
  u16* kb  = (u16*)alloc((size_t)MR * EMB * 2);
  u16* vb  = (u16*)alloc((size_t)MR * EMB * 2);
  u16* Wqt = (u16*)alloc((size_t)EMB * EMB * 2);
  u16* Wkt = (u16*)alloc((size_t)KVD * EMB * 2);
  u16* Wvt = (u16*)alloc((size_t)KVD * EMB * 2);
  u16* Wot = (u16*)alloc((size_t)EMB * EMB * 2);
  u16* Qp  = (u16*)alloc((size_t)MR * EMB * 2);
  u16* Kpp = (u16*)alloc((size_t)MR * KVD * 2);
  u16* Vpp = (u16*)alloc((size_t)MR * KVD * 2);
  u16* Vtt = (u16*)alloc((size_t)MR * KVD * 2);
  u16* Y   = qb;  // qb dead after Q projection
  if (off > ws_size) return;  // loud failure instead of OOB corruption

  const int n8 = MR * EMB / 8;
  cvt_f32_bf16<<<n8 / 256, 256, 0, stream>>>(q_in, qb, n8);
  cvt_f32_bf16<<<n8 / 256, 256, 0, stream>>>(k_in, kb, n8);
  cvt_f32_bf16<<<n8 / 256, 256, 0, stream>>>(v_in, vb, n8);
  transp_cvt<<<dim3(EMB / 32, EMB / 32), dim3(32, 8), 0, stream>>>(Wq, Wqt, EMB, EMB);
  transp_cvt<<<dim3(KVD / 32, EMB / 32), dim3(32, 8), 0, stream>>>(Wk, Wkt, EMB, KVD);
  transp_cvt<<<dim3(KVD / 32, EMB / 32), dim3(32, 8), 0, stream>>>(Wv, Wvt, EMB, KVD);
  transp_cvt<<<dim3(EMB / 32, EMB / 32), dim3(32, 8), 0, stream>>>(Wo, Wot, EMB, EMB);

  gemm_bt<u16><<<dim3(EMB / 128, MR / 128), 256, 0, stream>>>(qb, Wqt, bq, Qp, MR, EMB, EMB);
  gemm_bt<u16><<<dim3(KVD / 128, MR / 128), 256, 0, stream>>>(kb, Wkt, bk, Kpp, MR, KVD, EMB);
  gemm_bt<u16><<<dim3(KVD / 128, MR / 128), 256, 0, stream>>>(vb, Wvt, bv, Vpp, MR, KVD, EMB);
  transp_v<<<dim3(SEQ / 32, HD / 32, BATCH * NKV), dim3(32, 8), 0, stream>>>(Vpp, Vtt);
  attn<<<dim3(SEQ / 128, BATCH * NQ), 256, 0, stream>>>(Qp, Kpp, Vtt, Y);
  gemm_bt<float><<<dim3(EMB / 128, MR / 128), 256, 0, stream>>>(Y, Wot, bo, out, MR, EMB, EMB);
}

// Round 2
// 789.468 us; speedup vs baseline: 1.0984x; 1.0984x over previous
//
#include <hip/hip_runtime.h>

typedef unsigned short u16;
typedef __attribute__((ext_vector_type(8))) short s16x8;
typedef __attribute__((ext_vector_type(4))) short s16x4;
typedef __attribute__((ext_vector_type(4))) float f32x4;

#define DEVI static __device__ __forceinline__

constexpr int BATCH = 2;
constexpr int SEQ   = 2048;
constexpr int EMB   = 4096;
constexpr int NQ    = 32;
constexpr int NKV   = 8;
constexpr int HD    = 128;
constexpr int KVD   = 1024;
constexpr int MR    = BATCH * SEQ;   // 4096 rows for all projections

// ---------- helpers ----------

DEVI u16 f2bf(float f) {             // RNE float -> bf16 (finite inputs)
  union { float f; unsigned u; } x; x.f = f;
  unsigned r = x.u + 0x7FFFu + ((x.u >> 16) & 1u);
  return (u16)(r >> 16);
}

DEVI void mfma_acc(f32x4& c, s16x8 a, s16x8 b) {
  asm volatile("v_mfma_f32_16x16x32_bf16 %0, %1, %2, %0" : "+v"(c) : "v"(a), "v"(b));
}

DEVI void gload16(const void* g, void* l) {
  __builtin_amdgcn_global_load_lds(
      (const __attribute__((address_space(1))) void*)g,
      (__attribute__((address_space(3))) void*)l, 16, 0, 0);
}

DEVI float fexp2(float x) {
#if __has_builtin(__builtin_amdgcn_exp2f)
  return __builtin_amdgcn_exp2f(x);
#else
  return exp2f(x);
#endif
}

DEVI void store_out(u16* C, size_t idx, float v)   { C[idx] = f2bf(v); }
DEVI void store_out(float* C, size_t idx, float v) { C[idx] = v; }

// ---------- elementwise f32 -> bf16 ----------

__global__ __launch_bounds__(256) void cvt_f32_bf16(const float* __restrict__ in,
                                                    u16* __restrict__ out, int n8) {
  int i = blockIdx.x * 256 + threadIdx.x;
  if (i >= n8) return;
  const float4* p4 = (const float4*)in;
  float4 a = p4[2 * (size_t)i], b = p4[2 * (size_t)i + 1];
  u16 t[8];
  t[0] = f2bf(a.x); t[1] = f2bf(a.y); t[2] = f2bf(a.z); t[3] = f2bf(a.w);
  t[4] = f2bf(b.x); t[5] = f2bf(b.y); t[6] = f2bf(b.z); t[7] = f2bf(b.w);
  *(s16x8*)(out + 8 * (size_t)i) = *(const s16x8*)t;
}

// ---------- W[K][N] f32 -> Wt[N][K] bf16 (transpose + convert) ----------

__global__ __launch_bounds__(256) void transp_cvt(const float* __restrict__ W,
                                                  u16* __restrict__ Wt,
                                                  int Kd, int Nd) {
  __shared__ u16 tile[32][33];
  int tx = threadIdx.x, ty = threadIdx.y;
  int n0 = blockIdx.x * 32, k0 = blockIdx.y * 32;
#pragma unroll
  for (int j = 0; j < 4; ++j)
    tile[ty + 8 * j][tx] = f2bf(W[(size_t)(k0 + ty + 8 * j) * Nd + n0 + tx]);
  __syncthreads();
#pragma unroll
  for (int j = 0; j < 4; ++j)
    Wt[(size_t)(n0 + ty + 8 * j) * Kd + k0 + tx] = tile[tx][ty + 8 * j];
}

// ---------- Vp[B,S,KVD] bf16 -> Vt[B*NKV][HD][SEQ] bf16 ----------

__global__ __launch_bounds__(256) void transp_v(const u16* __restrict__ Vp,
                                                u16* __restrict__ Vt) {
  __shared__ u16 tile[32][33];
  int tx = threadIdx.x, ty = threadIdx.y;
  int bh = blockIdx.z, b = bh >> 3, h = bh & 7;
  int s0 = blockIdx.x * 32, d0 = blockIdx.y * 32;
  const u16* src = Vp + (size_t)b * SEQ * KVD + h * HD;
#pragma unroll
  for (int j = 0; j < 4; ++j)
    tile[ty + 8 * j][tx] = src[(size_t)(s0 + ty + 8 * j) * KVD + d0 + tx];
  __syncthreads();
  u16* dst = Vt + (size_t)bh * HD * SEQ;
#pragma unroll
  for (int j = 0; j < 4; ++j)
    dst[(size_t)(d0 + ty + 8 * j) * SEQ + s0 + tx] = tile[tx][ty + 8 * j];
}

// ---------- GEMM: C[M][N] = A[M][K] * Bt[N][K]^T + bias, bf16 MFMA ----------
// (unchanged from round 1 — 128x128 tile, BK=32, global_load_lds staging)

template <typename OT>
__global__ __launch_bounds__(256) void gemm_bt(const u16* __restrict__ A,
                                               const u16* __restrict__ Bt,
                                               const float* __restrict__ bias,
                                               OT* __restrict__ C,
                                               int M, int N, int K) {
  __shared__ __align__(16) u16 As[128 * 32];
  __shared__ __align__(16) u16 Bs[128 * 32];
  const int tid = threadIdx.x;
  const int lane = tid & 63, w = tid >> 6;
  const int wr = w >> 1, wc = w & 1;
  const int l15 = lane & 15, g = lane >> 4;
  const int m0 = blockIdx.y * 128, n0 = blockIdx.x * 128;
  const int srow = lane >> 2, schunk = lane & 3;
  const int fsw = (srow ^ (srow >> 2)) & 3;
  const int fr  = (l15  ^ (l15  >> 2)) & 3;

  f32x4 acc[4][4] = {};

  const u16* Ag = A  + (size_t)(m0 + w * 32 + srow) * K + ((schunk ^ fsw) << 3);
  const u16* Bg = Bt + (size_t)(n0 + w * 32 + srow) * K + ((schunk ^ fsw) << 3);
  u16* Al = As + (w * 32) * 32;
  u16* Bl = Bs + (w * 32) * 32;

  for (int k0 = 0; k0 < K; k0 += 32) {
    __syncthreads();
    gload16(Ag + k0,                    Al);
    gload16(Ag + (size_t)16 * K + k0,   Al + 16 * 32);
    gload16(Bg + k0,                    Bl);
    gload16(Bg + (size_t)16 * K + k0,   Bl + 16 * 32);
    __syncthreads();

    s16x8 af[4], bfr[4];
#pragma unroll
    for (int rt = 0; rt < 4; ++rt)
      af[rt] = *(const s16x8*)(As + (wr * 64 + rt * 16 + l15) * 32 + ((g ^ fr) << 3));
#pragma unroll
    for (int ct = 0; ct < 4; ++ct)
      bfr[ct] = *(const s16x8*)(Bs + (wc * 64 + ct * 16 + l15) * 32 + ((g ^ fr) << 3));
#pragma unroll
    for (int rt = 0; rt < 4; ++rt)
#pragma unroll
      for (int ct = 0; ct < 4; ++ct)
        mfma_acc(acc[rt][ct], af[rt], bfr[ct]);
  }

#pragma unroll
  for (int ct = 0; ct < 4; ++ct) {
    const int col = n0 + wc * 64 + ct * 16 + l15;
    const float bv = bias[col];
#pragma unroll
    for (int rt = 0; rt < 4; ++rt) {
      const int row = m0 + wr * 64 + rt * 16 + g * 4;
#pragma unroll
      for (int i = 0; i < 4; ++i)
        store_out(C, (size_t)(row + i) * N + col, acc[rt][ct][i] + bv);
    }
  }
}

// ---------- flash attention (GQA), swapped-operand structure ----------
// Grid: (SEQ/128, BATCH*NQ). 4 waves x 32 q-rows. KV chunk = 64, double-buffered.
// QK^T computed as mfma(K,Q) -> S^T: lane (g,l15) holds S[q=rt*16+l15][kv=ct*16+g*4+i].
// Softmax per q-row = in-register reduce + 2 shfl_xor (over g). P^T packed via
// v_cvt_pk_bf16_f32, routed to the PV B-fragment with ds_bpermute (no LDS P).
// PV computed as mfma(V^T,P^T) -> O^T: lane holds O[q=rt*16+l15][d=dt*16+g*4+i].
// K/V staged global_load_lds(16B), XOR block swizzle blk^=(row&7) on BOTH sides.

__global__ __launch_bounds__(256, 2) void attn(const u16* __restrict__ Q,
                                               const u16* __restrict__ Kp,
                                               const u16* __restrict__ Vt,
                                               u16* __restrict__ Y) {
  __shared__ __align__(16) u16 Kb[2][64 * 128];   // [buf][kv][d]   (swizzled)
  __shared__ __align__(16) u16 Vb[2][128 * 64];   // [buf][d][kv]   (swizzled)

  const int tid = threadIdx.x, lane = tid & 63, w = tid >> 6;
  const int l15 = lane & 15, g = lane >> 4;
  const int g0 = g & 1, g1 = g >> 1;
  const int bz = blockIdx.y, b = bz >> 5, qh = bz & 31, h = qh >> 2;
  const int q0 = blockIdx.x * 128;
  constexpr float C1 = 0.08838834764831845f * 1.4426950408889634f; // scale*log2e

  // Q fragments (B-operand layout: lane holds Q[q=l15][k=g*8..g*8+7])
  s16x8 qf[2][4];
  const u16* qptr = Q + (size_t)(b * SEQ + q0 + w * 32) * EMB + qh * HD;
#pragma unroll
  for (int rt = 0; rt < 2; ++rt)
#pragma unroll
    for (int ks = 0; ks < 4; ++ks)
      qf[rt][ks] = *(const s16x8*)(qptr + (size_t)(rt * 16 + l15) * EMB + ks * 32 + g * 8);

  const u16* kbase = Kp + (size_t)b * SEQ * KVD + h * HD;
  const u16* vbase = Vt + (size_t)(b * NKV + h) * HD * SEQ;

  // Stage one KV chunk into buf via global_load_lds.
  // Dest is wave-uniform; HW writes lane*16B. Source col pre-swizzled so that
  // LDS block j of row r holds global block j^(r&7)  (involution, G21).
  auto stage = [&](int buf, int kv0) {
#pragma unroll
    for (int p = 0; p < 4; ++p) {               // K: 64 rows x 128 u16
      int r = p * 16 + w * 4 + (lane >> 4);
      const u16* src = kbase + (size_t)(kv0 + r) * KVD + (((lane & 15) ^ (r & 7)) << 3);
      gload16(src, &Kb[buf][p * 2048 + w * 512]);
    }
#pragma unroll
    for (int p = 0; p < 4; ++p) {               // V^T: 128 rows x 64 u16
      int r = p * 32 + w * 8 + (lane >> 3);
      const u16* src = vbase + (size_t)r * SEQ + kv0 + (((lane & 7) ^ (r & 7)) << 3);
      gload16(src, &Vb[buf][p * 2048 + w * 512]);
    }
  };

  // bpermute source lanes: 32*g0 + 16*u + l15  (u = word>>1)
  const int addrA = (((g0 << 5) | l15)) << 2;        // u=0
  const int addrB = (((g0 << 5) | 16 | l15)) << 2;   // u=1

  f32x4 o[2][8] = {};
  float m_[2] = {-1e30f, -1e30f}, l_[2] = {0.f, 0.f};

  stage(0, 0);
  __syncthreads();

  for (int t = 0; t < SEQ / 64; ++t) {
    const int cur = t & 1;
    if (t < SEQ / 64 - 1) stage(cur ^ 1, (t + 1) * 64);  // prefetch next chunk

    // ---- S^T = K Q^T ----
    f32x4 sacc[2][4] = {};
    __builtin_amdgcn_s_setprio(1);
#pragma unroll
    for (int ks = 0; ks < 4; ++ks) {
      s16x8 kf[4];
#pragma unroll
      for (int ct = 0; ct < 4; ++ct) {
        const int blk = ((ks << 2) | g) ^ (l15 & 7);
        kf[ct] = *(const s16x8*)&Kb[cur][(ct * 16 + l15) * 128 + (blk << 3)];
      }
#pragma unroll
      for (int rt = 0; rt < 2; ++rt)
#pragma unroll
        for (int ct = 0; ct < 4; ++ct)
          mfma_acc(sacc[rt][ct], kf[ct], qf[rt][ks]);
    }
    __builtin_amdgcn_s_setprio(0);

    // ---- online softmax (per q-row, mostly in-register) + P routing ----
    s16x8 pvf[2][2];
#pragma unroll
    for (int rt = 0; rt < 2; ++rt) {
      float mx = -1e30f;
#pragma unroll
      for (int ct = 0; ct < 4; ++ct)
#pragma unroll
        for (int i = 0; i < 4; ++i) mx = fmaxf(mx, sacc[rt][ct][i]);
      mx *= C1;
      mx = fmaxf(mx, __shfl_xor(mx, 16));
      mx = fmaxf(mx, __shfl_xor(mx, 32));
      const float mn = fmaxf(m_[rt], mx);
      const float al = fexp2(m_[rt] - mn);
      m_[rt] = mn;

      float rs = 0.f;
      int wd[4][2];
#pragma unroll
      for (int ct = 0; ct < 4; ++ct) {
        float p0 = fexp2(sacc[rt][ct][0] * C1 - mn);
        float p1 = fexp2(sacc[rt][ct][1] * C1 - mn);
        float p2 = fexp2(sacc[rt][ct][2] * C1 - mn);
        float p3 = fexp2(sacc[rt][ct][3] * C1 - mn);
        rs += (p0 + p1) + (p2 + p3);
        asm("v_cvt_pk_bf16_f32 %0, %1, %2" : "=v"(wd[ct][0]) : "v"(p0), "v"(p1));
        asm("v_cvt_pk_bf16_f32 %0, %1, %2" : "=v"(wd[ct][1]) : "v"(p2), "v"(p3));
      }
      rs += __shfl_xor(rs, 16);
      rs += __shfl_xor(rs, 32);
      l_[rt] = l_[rt] * al + rs;
#pragma unroll
      for (int dt = 0; dt < 8; ++dt) {
        o[rt][dt][0] *= al; o[rt][dt][1] *= al;
        o[rt][dt][2] *= al; o[rt][dt][3] *= al;
      }

      // route: target word t'=2u+s of lane(g1,g0,l15) = wd[2*ks2+g1][s] @ lane 32*g0+16*u+l15
#pragma unroll
      for (int ks2 = 0; ks2 < 2; ++ks2) {
        union { int w4[4]; s16x8 v; } u;
#pragma unroll
        for (int s = 0; s < 2; ++s) {
          const int c0 = wd[2 * ks2][s], c1 = wd[2 * ks2 + 1][s];
          const int r0 = __builtin_amdgcn_ds_bpermute(addrA, c0);
          const int r1 = __builtin_amdgcn_ds_bpermute(addrA, c1);
          u.w4[s] = g1 ? r1 : r0;
          const int r2 = __builtin_amdgcn_ds_bpermute(addrB, c0);
          const int r3 = __builtin_amdgcn_ds_bpermute(addrB, c1);
          u.w4[2 + s] = g1 ? r3 : r2;
        }
        pvf[rt][ks2] = u.v;
      }
    }

    // ---- O^T += V^T P^T ----
    __builtin_amdgcn_s_setprio(1);
#pragma unroll
    for (int ks2 = 0; ks2 < 2; ++ks2)
#pragma unroll
      for (int dt = 0; dt < 8; ++dt) {
        const int blk = ((ks2 << 2) | g) ^ (l15 & 7);
        const s16x8 vf = *(const s16x8*)&Vb[cur][(dt * 16 + l15) * 64 + (blk << 3)];
        mfma_acc(o[0][dt], vf, pvf[0][ks2]);
        mfma_acc(o[1][dt], vf, pvf[1][ks2]);
      }
    __builtin_amdgcn_s_setprio(0);

    __syncthreads();   // staged chunk t+1 visible; all reads of buf done
  }

  // ---- epilogue: Y[q][d], 8B vector stores ----
  u16* ybase = Y + (size_t)(b * SEQ + q0 + w * 32) * EMB + qh * HD;
#pragma unroll
  for (int rt = 0; rt < 2; ++rt) {
    const float inv = 1.f / l_[rt];
    u16* yr = ybase + (size_t)(rt * 16 + l15) * EMB + g * 4;
#pragma unroll
    for (int dt = 0; dt < 8; ++dt) {
      u16 t4[4];
#pragma unroll
      for (int i = 0; i < 4; ++i) t4[i] = f2bf(o[rt][dt][i] * inv);
      *(s16x4*)(yr + dt * 16) = *(const s16x4*)t4;
    }
  }
}

// ---------- launch ----------

extern "C" void kernel_launch(void* const* d_in, const int* in_sizes, int n_in,
                              void* d_out, int out_size, void* d_ws, size_t ws_size,
                              hipStream_t stream) {
  (void)in_sizes; (void)n_in; (void)out_size;
  const float* q_in = (const float*)d_in[0];
  const float* k_in = (const float*)d_in[1];
  const float* v_in = (const float*)d_in[2];
  const float* Wq = (const float*)d_in[3];
  const float* bq = (const float*)d_in[4];
  const float* Wk = (const float*)d_in[5];
  const float* bk = (const float*)d_in[6];
  const float* Wv = (const float*)d_in[7];
  const float* bv = (const float*)d_in[8];
  const float* Wo = (const float*)d_in[9];
  const float* bo = (const float*)d_in[10];
  float* out = (float*)d_out;

  char* base = (char*)d_ws;
  size_t off = 0;
  auto alloc = [&](size_t bytes) -> void* {
    void* r = base + off;
    off += (bytes + 255) & ~(size_t)255;
    return r;
  };
  u16* qb  = (u16*)alloc((size_t)MR * EMB * 2);
  u16* kb  = (u16*)alloc((size_t)MR * EMB * 2);
  u16* vb  = (u16*)alloc((size_t)MR * EMB * 2);
  u16* Wqt = (u16*)alloc((size_t)EMB * EMB * 2);
  u16* Wkt = (u16*)alloc((size_t)KVD * EMB * 2);
  u16* Wvt = (u16*)alloc((size_t)KVD * EMB * 2);
  u16* Wot = (u16*)alloc((size_t)EMB * EMB * 2);
  u16* Qp  = (u16*)alloc((size_t)MR * EMB * 2);
  u16* Kpp = (u16*)alloc((size_t)MR * KVD * 2);
  u16* Vpp = (u16*)alloc((size_t)MR * KVD * 2);
  u16* Vtt = (u16*)alloc((size_t)MR * KVD * 2);
  u16* Y   = qb;  // qb dead after Q projection
  if (off > ws_size) return;  // loud failure instead of OOB corruption

  const int n8 = MR * EMB / 8;
  cvt_f32_bf16<<<n8 / 256, 256, 0, stream>>>(q_in, qb, n8);
  cvt_f32_bf16<<<n8 / 256, 256, 0, stream>>>(k_in, kb, n8);
  cvt_f32_bf16<<<n8 / 256, 256, 0, stream>>>(v_in, vb, n8);
  transp_cvt<<<dim3(EMB / 32, EMB / 32), dim3(32, 8), 0, stream>>>(Wq, Wqt, EMB, EMB);
  transp_cvt<<<dim3(KVD / 32, EMB / 32), dim3(32, 8), 0, stream>>>(Wk, Wkt, EMB, KVD);
  transp_cvt<<<dim3(KVD / 32, EMB / 32), dim3(32, 8), 0, stream>>>(Wv, Wvt, EMB, KVD);
  transp_cvt<<<dim3(EMB / 32, EMB / 32), dim3(32, 8), 0, stream>>>(Wo, Wot, EMB, EMB);

  gemm_bt<u16><<<dim3(EMB / 128, MR / 128), 256, 0, stream>>>(qb, Wqt, bq, Qp, MR, EMB, EMB);
  gemm_bt<u16><<<dim3(KVD / 128, MR / 128), 256, 0, stream>>>(kb, Wkt, bk, Kpp, MR, KVD, EMB);
  gemm_bt<u16><<<dim3(KVD / 128, MR / 128), 256, 0, stream>>>(vb, Wvt, bv, Vpp, MR, KVD, EMB);
  transp_v<<<dim3(SEQ / 32, HD / 32, BATCH * NKV), dim3(32, 8), 0, stream>>>(Vpp, Vtt);
  attn<<<dim3(SEQ / 128, BATCH * NQ), 256, 0, stream>>>(Qp, Kpp, Vtt, Y);
  gemm_bt<float><<<dim3(EMB / 128, MR / 128), 256, 0, stream>>>(Y, Wot, bo, out, MR, EMB, EMB);
}